// Round 16
// baseline (149.461 us; speedup 1.0000x reference)
//
#include <hip/hip_runtime.h>
#include <hip/hip_bf16.h>

#define TOK   8192      // B*T
#define NVAR  32
#define DDIM  64
#define HDIM  128
#define CDIM  64
#define ND    2048      // N*D
#define LN_EPS 1e-5f
#define TTV   32        // k_var token tile

typedef float f32x4 __attribute__((ext_vector_type(4)));
typedef short s16x8 __attribute__((ext_vector_type(8)));
typedef unsigned short u16x8 __attribute__((ext_vector_type(8)));

__device__ __forceinline__ float bf2f(unsigned short u) {
    unsigned int x = ((unsigned int)u) << 16;
    return __uint_as_float(x);
}
// native RNE conversion -> compiler emits v_cvt_pk_bf16_f32 for adjacent pairs
__device__ __forceinline__ unsigned short f2bf(float f) {
    __hip_bfloat16 h = __float2bfloat16(f);
    return __builtin_bit_cast(unsigned short, h);
}
__device__ __forceinline__ float elu_f(float x) {
    return x > 0.f ? x : (__expf(x) - 1.f);
}
__device__ __forceinline__ float sigm_f(float x) {
    return 1.f / (1.f + __expf(-x));
}
__device__ __forceinline__ s16x8 frag_ld(const unsigned short* p) {
    return __builtin_bit_cast(s16x8, *(const u16x8*)p);
}
__device__ __forceinline__ f32x4 mfma_bf16(s16x8 a, s16x8 b, f32x4 c) {
    return __builtin_amdgcn_mfma_f32_16x16x32_bf16(a, b, c, 0, 0, 0);
}

// ---------------- fused pack: all 8 weight tensors -> frag-major bf16 ----------------
__global__ __launch_bounds__(256) void k_pack_all(
        const float* __restrict__ vW1, const float* __restrict__ vWsk,
        const float* __restrict__ vW2, const float* __restrict__ vWg,
        const float* __restrict__ fW1, const float* __restrict__ fWsk,
        const float* __restrict__ fW2, const float* __restrict__ fWg,
        unsigned short* __restrict__ pk1, unsigned short* __restrict__ pksk,
        unsigned short* __restrict__ pk2, unsigned short* __restrict__ pkg,
        unsigned short* __restrict__ pfW1, unsigned short* __restrict__ pfWsk,
        unsigned short* __restrict__ pfW2, unsigned short* __restrict__ pfWg) {
    int sg = blockIdx.x * 4 + (threadIdx.x >> 6);
    int lane = threadIdx.x & 63;
    const float* W; unsigned short* out; int K, N, NF, n, bx;
    if (sg < 512)       {                 W = vW1;  out = pk1;  K = 64;   N = 128; NF = 8;  n = sg >> 4;  bx = sg & 15; }
    else if (sg < 1024) { int i = sg - 512;  W = vWsk; out = pksk; K = 64;   N = 128; NF = 8;  n = i >> 4; bx = i & 15; }
    else if (sg < 2048) { int i = sg - 1024; W = vW2;  out = pk2;  K = 128;  N = 128; NF = 8;  n = i >> 5; bx = i & 31; }
    else if (sg < 4096) { int i = sg - 2048; W = vWg;  out = pkg;  K = 128;  N = 256; NF = 16; n = i >> 6; bx = i & 63; }
    else if (sg < 4608) { int i = sg - 4096; W = fW1;  out = pfW1; K = 2048; N = 128; NF = 8;  n = 0;      bx = i; }
    else if (sg < 4736) { int i = sg - 4608; W = fWsk; out = pfWsk; K = 2048; N = 32; NF = 2;  n = 0;      bx = i; }
    else if (sg < 4768) { int i = sg - 4736; W = fW2;  out = pfW2; K = 128;  N = 128; NF = 8;  n = 0;      bx = i; }
    else                { int i = sg - 4768; W = fWg;  out = pfWg; K = 128;  N = 64;  NF = 4;  n = 0;      bx = i; }
    int ks = bx / NF, nf = bx - ks * NF;
    int col = nf * 16 + (lane & 15);
    int k0 = ks * 32 + (lane >> 4) * 8;
    const float* src = W + (size_t)n * K * N + (size_t)k0 * N + col;
    unsigned short* dst = out + (size_t)n * K * N + ((size_t)bx * 64 + lane) * 8;
    unsigned short v[8];
#pragma unroll
    for (int j = 0; j < 8; ++j) v[j] = f2bf(src[(size_t)j * N]);
    *(u16x8*)dst = *(const u16x8*)v;
}

// ---------------- fused flatten GRN + selection (structure unchanged from r12) ----------------
__global__ __launch_bounds__(256) void k_fsel(const float* __restrict__ emb,
        const float* __restrict__ ctx, const float* __restrict__ fWc,
        const unsigned short* __restrict__ pfW1, const unsigned short* __restrict__ pfWsk,
        const float* __restrict__ fb1, const float* __restrict__ fbsk,
        const unsigned short* __restrict__ pfW2, const float* __restrict__ fb2,
        const unsigned short* __restrict__ pfWg, const float* __restrict__ fbg,
        const float* __restrict__ fg, const float* __restrict__ fb,
        float* __restrict__ wout) {
    __shared__ __align__(16) unsigned short pool[21376];
    float* CTX = (float*)pool;              // [128]
    float* PRT = (float*)(pool + 256);      // [2][64][40]
    unsigned short* H1 = pool + 10496;      // [32][136]
    unsigned short* H2 = pool + 14848;      // [32][136]
    float* SK = (float*)(pool + 19200);     // [32][34]
    float* G  = (float*)(pool + 10496);     // [32][68], overlays H1 only

    const int tid = threadIdx.x;
    const int lane = tid & 63;
    const int w4 = tid >> 6;
    const int mh = w4 & 1;
    const int kh = w4 >> 1;
    const int lr = lane & 15, lk = lane >> 4;
    const int tok0 = blockIdx.x * 32;
    const int b = tok0 >> 7;

    if (tid < 128) {
        float acc0 = 0.f;
        const float* cr = ctx + b * CDIM;
#pragma unroll 8
        for (int c = 0; c < CDIM; ++c) acc0 += cr[c] * fWc[c * HDIM + tid];
        CTX[tid] = acc0;
    }

    const float* arow = emb + (size_t)(tok0 + mh * 16 + lr) * ND + kh * 1024 + lk * 8;
    f32x4 acc[10] = {};
    for (int ks = 0; ks < 32; ++ks) {
        const int ksg = kh * 32 + ks;
        float4 a0 = *(const float4*)(arow + ks * 32);
        float4 a1 = *(const float4*)(arow + ks * 32 + 4);
        unsigned short av[8];
        av[0] = f2bf(a0.x); av[1] = f2bf(a0.y); av[2] = f2bf(a0.z); av[3] = f2bf(a0.w);
        av[4] = f2bf(a1.x); av[5] = f2bf(a1.y); av[6] = f2bf(a1.z); av[7] = f2bf(a1.w);
        s16x8 af = __builtin_bit_cast(s16x8, *(u16x8*)av);
#pragma unroll
        for (int nf = 0; nf < 8; ++nf) {
            s16x8 bf = frag_ld(pfW1 + ((size_t)(ksg * 8 + nf) * 64 + lane) * 8);
            acc[nf] = mfma_bf16(af, bf, acc[nf]);
        }
#pragma unroll
        for (int nf = 0; nf < 2; ++nf) {
            s16x8 bf = frag_ld(pfWsk + ((size_t)(ksg * 2 + nf) * 64 + lane) * 8);
            acc[8 + nf] = mfma_bf16(af, bf, acc[8 + nf]);
        }
    }

    if (w4 >= 2) {
        float* p = PRT + ((size_t)mh * 64 + lane) * 40;
#pragma unroll
        for (int f = 0; f < 10; ++f) *(f32x4*)(p + f * 4) = acc[f];
    }
    __syncthreads();
    if (w4 < 2) {
        const float* p = PRT + ((size_t)mh * 64 + lane) * 40;
#pragma unroll
        for (int f = 0; f < 10; ++f) acc[f] = acc[f] + *(const f32x4*)(p + f * 4);

#pragma unroll
        for (int nf = 0; nf < 8; ++nf) {
            int col = nf * 16 + lr;
            float add = fb1[col] + CTX[col];
#pragma unroll
            for (int r = 0; r < 4; ++r)
                H1[(mh * 16 + lk * 4 + r) * 136 + col] = f2bf(elu_f(acc[nf][r] + add));
        }
#pragma unroll
        for (int nf = 0; nf < 2; ++nf) {
            int col = nf * 16 + lr;
            float add = fbsk[col];
#pragma unroll
            for (int r = 0; r < 4; ++r)
                SK[(mh * 16 + lk * 4 + r) * 34 + col] = acc[8 + nf][r] + add;
        }
    }
    __syncthreads();

    if (tid < 128) {
        const int w = w4;
        f32x4 a2[8] = {};
#pragma unroll
        for (int ks = 0; ks < 4; ++ks) {
            s16x8 af = frag_ld(H1 + (w * 16 + lr) * 136 + ks * 32 + lk * 8);
#pragma unroll
            for (int nf = 0; nf < 8; ++nf) {
                s16x8 bf = frag_ld(pfW2 + ((size_t)(ks * 8 + nf) * 64 + lane) * 8);
                a2[nf] = mfma_bf16(af, bf, a2[nf]);
            }
        }
#pragma unroll
        for (int nf = 0; nf < 8; ++nf) {
            int col = nf * 16 + lr;
            float add = fb2[col];
#pragma unroll
            for (int r = 0; r < 4; ++r)
                H2[(w * 16 + lk * 4 + r) * 136 + col] = f2bf(a2[nf][r] + add);
        }
    }
    __syncthreads();

    if (tid < 128) {
        const int w = w4;
        f32x4 a3[4] = {};
#pragma unroll
        for (int ks = 0; ks < 4; ++ks) {
            s16x8 af = frag_ld(H2 + (w * 16 + lr) * 136 + ks * 32 + lk * 8);
#pragma unroll
            for (int nf = 0; nf < 4; ++nf) {
                s16x8 bf = frag_ld(pfWg + ((size_t)(ks * 4 + nf) * 64 + lane) * 8);
                a3[nf] = mfma_bf16(af, bf, a3[nf]);
            }
        }
#pragma unroll
        for (int nf = 0; nf < 4; ++nf) {
            int col = nf * 16 + lr;
            float add = fbg[col];
#pragma unroll
            for (int r = 0; r < 4; ++r)
                G[(w * 16 + lk * 4 + r) * 68 + col] = a3[nf][r] + add;
        }
    }
    __syncthreads();

    if (tid < 128) {
        int grp = tid >> 5, t = tid & 31;
        float fgv = fg[t], fbv = fb[t];
#pragma unroll 2
        for (int j = 0; j < 8; ++j) {
            int tr = grp * 8 + j;
            float a = G[tr * 68 + t];
            float bb = G[tr * 68 + 32 + t];
            float val = a * sigm_f(bb) + SK[tr * 34 + t];
            float s = val, q = val * val;
#pragma unroll
            for (int m = 16; m >= 1; m >>= 1) { s += __shfl_xor(s, m, 32); q += __shfl_xor(q, m, 32); }
            float mean = s * (1.f / 32.f);
            float var = q * (1.f / 32.f) - mean * mean;
            float logit = (val - mean) * rsqrtf(var + LN_EPS) * fgv + fbv;
            float mx = logit;
#pragma unroll
            for (int m = 16; m >= 1; m >>= 1) mx = fmaxf(mx, __shfl_xor(mx, m, 32));
            float e = __expf(logit - mx);
            float se = e;
#pragma unroll
            for (int m = 16; m >= 1; m >>= 1) se += __shfl_xor(se, m, 32);
            wout[(size_t)(tok0 + tr) * NVAR + t] = e / se;
        }
    }
}

// ---------------- per-variable GRNs: r15 structure, native bf16 converts ----------------
// TT=32: grid dim3(256 tiles, 4 groups of 8 n) = 1024 blocks, 4 waves.
// Cross-barrier register prefetch (r14/r15):
//   iter-top:  ph2's 8 W2-frags -> w2p; combine's wsel/gam/bet scalars
//   ph2-top:   ph3's 16 Wg-frags -> wgp; next-n E (T14)
// LDS 14592 B: EB[32][72]@0, VHB[32][136]@2304us (VH then VH2),
//              LNp[32][4][2]f32@6656us, LNm[32][2]f32@7168us
__global__ __launch_bounds__(256, 2) void k_var(
        const float* __restrict__ emb,
        const unsigned short* __restrict__ pk1, const unsigned short* __restrict__ pksk,
        const unsigned short* __restrict__ pk2, const unsigned short* __restrict__ pkg,
        const float* __restrict__ vb1, const float* __restrict__ vbsk,
        const float* __restrict__ vb2, const float* __restrict__ vbg,
        const float* __restrict__ gam, const float* __restrict__ bet,
        const float* __restrict__ wsel, float* __restrict__ outp) {
    __shared__ __align__(16) unsigned short pool[7296];
    unsigned short* EB  = pool;                  // [32][72]
    unsigned short* VHB = pool + 2304;           // [32][136]  VH (ph1-2) then VH2 (ph2-3)
    float* LNp = (float*)(pool + 6656);          // [32][4][2]
    float* LNm = (float*)(pool + 7168);          // [32][2]

    const int tid = threadIdx.x;
    const int lane = tid & 63;
    const int w = tid >> 6;
    const int lr = lane & 15;
    const int lk = lane >> 4;
    const int tok0 = blockIdx.x * TTV;
    const int gbase = blockIdx.y * 8;

    const int prow = tid >> 3, pc0 = (tid & 7) * 8;

    float accO[2][2][4] = {};

    // ---- initial stage: E tile for n=gbase ----
    {
        const float* src = emb + ((size_t)(tok0 + prow) * NVAR + gbase) * DDIM + pc0;
        unsigned short* dst = EB + prow * 72 + pc0;
#pragma unroll
        for (int q = 0; q < 2; ++q) {
            float4 v = *(const float4*)(src + q * 4);
            ushort4 t;
            t.x = f2bf(v.x); t.y = f2bf(v.y); t.z = f2bf(v.z); t.w = f2bf(v.w);
            *(ushort4*)(dst + q * 4) = t;
        }
    }
    __syncthreads();

    for (int nn = 0; nn < 8; ++nn) {
        const int n = gbase + nn;

        // ---- iter-top prefetch: ph2 W2-frags + combine scalars ----
        s16x8 w2p[8];
#pragma unroll
        for (int ks = 0; ks < 4; ++ks) {
            const unsigned short* p2 = pk2 + (size_t)n * 16384 + ((size_t)(ks * 8 + w * 2) * 64 + lane) * 8;
            w2p[ks * 2]     = frag_ld(p2);
            w2p[ks * 2 + 1] = frag_ld(p2 + 512);
        }
        float wselp[2][4];
#pragma unroll
        for (int mf = 0; mf < 2; ++mf)
#pragma unroll
            for (int r = 0; r < 4; ++r)
                wselp[mf][r] = wsel[(size_t)(tok0 + mf * 16 + lk * 4 + r) * NVAR + n];
        const float ga0 = gam[n * HDIM + w * 32 + lr];
        const float ga1 = gam[n * HDIM + w * 32 + 16 + lr];
        const float be0 = bet[n * HDIM + w * 32 + lr];
        const float be1 = bet[n * HDIM + w * 32 + 16 + lr];

        // ---- phase 1: VH = elu(E@W1+b1) -> VHB;  VS -> REGISTERS ----
        f32x4 c2[2][2];
#pragma unroll
        for (int mf = 0; mf < 2; ++mf)
#pragma unroll
            for (int nf = 0; nf < 2; ++nf) c2[mf][nf] = (f32x4){0.f, 0.f, 0.f, 0.f};
        {
            f32x4 c1[2][2] = {};
#pragma unroll
            for (int ks = 0; ks < 2; ++ks) {
                s16x8 af[2];
#pragma unroll
                for (int mf = 0; mf < 2; ++mf)
                    af[mf] = frag_ld(EB + (mf * 16 + lr) * 72 + ks * 32 + lk * 8);
                const unsigned short* p1 = pk1 + (size_t)n * 8192 + ((size_t)(ks * 8 + w * 2) * 64 + lane) * 8;
                const unsigned short* ps = pksk + (size_t)n * 8192 + ((size_t)(ks * 8 + w * 2) * 64 + lane) * 8;
                s16x8 b10 = frag_ld(p1), b11 = frag_ld(p1 + 512);
                s16x8 bs0 = frag_ld(ps), bs1 = frag_ld(ps + 512);
#pragma unroll
                for (int mf = 0; mf < 2; ++mf) {
                    c1[mf][0] = mfma_bf16(af[mf], b10, c1[mf][0]);
                    c1[mf][1] = mfma_bf16(af[mf], b11, c1[mf][1]);
                    c2[mf][0] = mfma_bf16(af[mf], bs0, c2[mf][0]);
                    c2[mf][1] = mfma_bf16(af[mf], bs1, c2[mf][1]);
                }
            }
#pragma unroll
            for (int nf = 0; nf < 2; ++nf) {
                int col = w * 32 + nf * 16 + lr;
                float bb1 = vb1[n * HDIM + col];
                float bbs = vbsk[n * HDIM + col];
#pragma unroll
                for (int mf = 0; mf < 2; ++mf) {
                    c2[mf][nf] = c2[mf][nf] + bbs;
#pragma unroll
                    for (int r = 0; r < 4; ++r)
                        VHB[(mf * 16 + lk * 4 + r) * 136 + col] = f2bf(elu_f(c1[mf][nf][r] + bb1));
                }
            }
        }
        __syncthreads();   // VH ready; EB dead

        // ---- ph2-top prefetch: FULL ph3 Wg frags + T14 next-n E ----
        s16x8 wgp[16];
#pragma unroll
        for (int ks = 0; ks < 4; ++ks) {
            const unsigned short* pg = pkg + (size_t)n * 32768;
            wgp[ks * 4]     = frag_ld(pg + ((size_t)(ks * 16 + 2 * w + 0) * 64 + lane) * 8);
            wgp[ks * 4 + 1] = frag_ld(pg + ((size_t)(ks * 16 + 2 * w + 1) * 64 + lane) * 8);
            wgp[ks * 4 + 2] = frag_ld(pg + ((size_t)(ks * 16 + 2 * w + 8) * 64 + lane) * 8);
            wgp[ks * 4 + 3] = frag_ld(pg + ((size_t)(ks * 16 + 2 * w + 9) * 64 + lane) * 8);
        }
        float4 pf0, pf1;
        if (nn < 7) {
            const float* src = emb + ((size_t)(tok0 + prow) * NVAR + n + 1) * DDIM + pc0;
            pf0 = *(const float4*)(src);
            pf1 = *(const float4*)(src + 4);
        }

        // ---- phase 2: VH2 = VH@W2+b2 into c3 regs (prefetched w2p) ----
        f32x4 c3[2][2] = {};
        {
#pragma unroll
            for (int ks = 0; ks < 4; ++ks) {
                s16x8 af[2];
#pragma unroll
                for (int mf = 0; mf < 2; ++mf)
                    af[mf] = frag_ld(VHB + (mf * 16 + lr) * 136 + ks * 32 + lk * 8);
#pragma unroll
                for (int mf = 0; mf < 2; ++mf) {
                    c3[mf][0] = mfma_bf16(af[mf], w2p[ks * 2], c3[mf][0]);
                    c3[mf][1] = mfma_bf16(af[mf], w2p[ks * 2 + 1], c3[mf][1]);
                }
            }
        }
        __syncthreads();   // all VH reads done -> VHB reusable

        // ---- write VH2 into VHB; stage prefetched E ----
        {
#pragma unroll
            for (int nf = 0; nf < 2; ++nf) {
                int col = w * 32 + nf * 16 + lr;
                float bb = vb2[n * HDIM + col];
#pragma unroll
                for (int mf = 0; mf < 2; ++mf)
#pragma unroll
                    for (int r = 0; r < 4; ++r)
                        VHB[(mf * 16 + lk * 4 + r) * 136 + col] = f2bf(c3[mf][nf][r] + bb);
            }
            if (nn < 7) {
                unsigned short* dst = EB + prow * 72 + pc0;
                ushort4 t;
                t.x = f2bf(pf0.x); t.y = f2bf(pf0.y); t.z = f2bf(pf0.z); t.w = f2bf(pf0.w);
                *(ushort4*)(dst) = t;
                t.x = f2bf(pf1.x); t.y = f2bf(pf1.y); t.z = f2bf(pf1.z); t.w = f2bf(pf1.w);
                *(ushort4*)(dst + 4) = t;
            }
        }
        __syncthreads();   // VH2 ready

        // ---- phase 3: VG in registers (all B-frags prefetched in wgp) ----
        float vv[2][2][4];
        float s_[2][4], q_[2][4];
        {
            f32x4 c4[2][4] = {};
#pragma unroll
            for (int ks = 0; ks < 4; ++ks) {
                s16x8 af[2];
#pragma unroll
                for (int mf = 0; mf < 2; ++mf)
                    af[mf] = frag_ld(VHB + (mf * 16 + lr) * 136 + ks * 32 + lk * 8);
#pragma unroll
                for (int mf = 0; mf < 2; ++mf) {
                    c4[mf][0] = mfma_bf16(af[mf], wgp[ks * 4],     c4[mf][0]);
                    c4[mf][1] = mfma_bf16(af[mf], wgp[ks * 4 + 1], c4[mf][1]);
                    c4[mf][2] = mfma_bf16(af[mf], wgp[ks * 4 + 2], c4[mf][2]);
                    c4[mf][3] = mfma_bf16(af[mf], wgp[ks * 4 + 3], c4[mf][3]);
                }
            }
            float bga0 = vbg[n * 256 + w * 32 + lr];
            float bga1 = vbg[n * 256 + w * 32 + 16 + lr];
            float bgb0 = vbg[n * 256 + 128 + w * 32 + lr];
            float bgb1 = vbg[n * 256 + 128 + w * 32 + 16 + lr];
#pragma unroll
            for (int mf = 0; mf < 2; ++mf)
#pragma unroll
                for (int r = 0; r < 4; ++r) {
                    float a0 = c4[mf][0][r] + bga0;
                    float b0 = c4[mf][2][r] + bgb0;
                    float x0 = a0 * sigm_f(b0) + c2[mf][0][r];
                    float a1 = c4[mf][1][r] + bga1;
                    float b1 = c4[mf][3][r] + bgb1;
                    float x1 = a1 * sigm_f(b1) + c2[mf][1][r];
                    vv[mf][0][r] = x0; vv[mf][1][r] = x1;
                    s_[mf][r] = x0 + x1;
                    q_[mf][r] = x0 * x0 + x1 * x1;
                }
#pragma unroll
            for (int mf = 0; mf < 2; ++mf)
#pragma unroll
                for (int r = 0; r < 4; ++r) {
#pragma unroll
                    for (int m = 1; m < 16; m <<= 1) {
                        s_[mf][r] += __shfl_xor(s_[mf][r], m);
                        q_[mf][r] += __shfl_xor(q_[mf][r], m);
                    }
                }
            if (lr == 0) {
#pragma unroll
                for (int mf = 0; mf < 2; ++mf)
#pragma unroll
                    for (int r = 0; r < 4; ++r) {
                        int row = mf * 16 + lk * 4 + r;
                        LNp[row * 8 + w * 2] = s_[mf][r];
                        LNp[row * 8 + w * 2 + 1] = q_[mf][r];
                    }
            }
        }
        __syncthreads();

        // ---- cross-wave LN finish ----
        if (tid < 128) {
            int row = tid >> 2, p = tid & 3;
            float ss = LNp[row * 8 + p * 2];
            float qq = LNp[row * 8 + p * 2 + 1];
            ss += __shfl_xor(ss, 1); qq += __shfl_xor(qq, 1);
            ss += __shfl_xor(ss, 2); qq += __shfl_xor(qq, 2);
            if (p == 0) {
                float mean = ss * (1.f / 128.f);
                float var = qq * (1.f / 128.f) - mean * mean;
                LNm[row * 2] = mean;
                LNm[row * 2 + 1] = rsqrtf(var + LN_EPS);
            }
        }
        __syncthreads();

        // ---- combine (scalars prefetched at iter-top) ----
        {
#pragma unroll
            for (int mf = 0; mf < 2; ++mf)
#pragma unroll
                for (int r = 0; r < 4; ++r) {
                    int row = mf * 16 + lk * 4 + r;
                    float mean = LNm[row * 2], inv = LNm[row * 2 + 1];
                    float wgt = wselp[mf][r];
                    accO[mf][0][r] += wgt * ((vv[mf][0][r] - mean) * inv * ga0 + be0);
                    accO[mf][1][r] += wgt * ((vv[mf][1][r] - mean) * inv * ga1 + be1);
                }
        }
    }

    // ---- one atomic per element per n-group ----
    {
#pragma unroll
        for (int mf = 0; mf < 2; ++mf)
#pragma unroll
            for (int r = 0; r < 4; ++r) {
                int row = mf * 16 + lk * 4 + r;
                float* po = outp + (size_t)(tok0 + row) * HDIM + w * 32 + lr;
                atomicAdd(po, accO[mf][0][r]);
                atomicAdd(po + 16, accO[mf][1][r]);
            }
    }
}

extern "C" void kernel_launch(void* const* d_in, const int* in_sizes, int n_in,
                              void* d_out, int out_size, void* d_ws, size_t ws_size,
                              hipStream_t stream) {
    const float* emb  = (const float*)d_in[0];
    const float* ctx  = (const float*)d_in[1];
    const float* fWsk = (const float*)d_in[2];
    const float* fbsk = (const float*)d_in[3];
    const float* fW1  = (const float*)d_in[4];
    const float* fb1  = (const float*)d_in[5];
    const float* fWc  = (const float*)d_in[6];
    const float* fW2  = (const float*)d_in[7];
    const float* fb2  = (const float*)d_in[8];
    const float* fWg  = (const float*)d_in[9];
    const float* fbg  = (const float*)d_in[10];
    const float* fg   = (const float*)d_in[11];
    const float* fb   = (const float*)d_in[12];
    const float* vWsk = (const float*)d_in[13];
    const float* vbsk = (const float*)d_in[14];
    const float* vW1  = (const float*)d_in[15];
    const float* vb1  = (const float*)d_in[16];
    const float* vW2  = (const float*)d_in[17];
    const float* vb2  = (const float*)d_in[18];
    const float* vWg  = (const float*)d_in[19];
    const float* vbg  = (const float*)d_in[20];
    const float* vgam = (const float*)d_in[21];
    const float* vbet = (const float*)d_in[22];

    float* outp = (float*)d_out;                       // [8192][128]
    float* wout = outp + (size_t)TOK * HDIM;           // [8192][32]

    unsigned short* pk1  = (unsigned short*)d_ws;      // [32][64][128]
    unsigned short* pksk = pk1 + 262144;               // [32][64][128]
    unsigned short* pk2  = pksk + 262144;              // [32][128][128]
    unsigned short* pkg  = pk2 + 524288;               // [32][128][256]
    unsigned short* pfW1 = pkg + 1048576;              // [2048][128]
    unsigned short* pfWsk= pfW1 + 262144;              // [2048][32]
    unsigned short* pfW2 = pfWsk + 65536;              // [128][128]
    unsigned short* pfWg = pfW2 + 16384;               // [128][64]

    hipMemsetAsync(d_out, 0, (size_t)TOK * HDIM * sizeof(float), stream);
    k_pack_all<<<1196, 256, 0, stream>>>(vW1, vWsk, vW2, vWg, fW1, fWsk, fW2, fWg,
                                         pk1, pksk, pk2, pkg, pfW1, pfWsk, pfW2, pfWg);
    k_fsel<<<256, 256, 0, stream>>>(emb, ctx, fWc, pfW1, pfWsk, fb1, fbsk,
                                    pfW2, fb2, pfWg, fbg, fg, fb, wout);
    k_var<<<dim3(TOK / TTV, 4), 256, 0, stream>>>(emb, pk1, pksk, pk2, pkg,
                                                  vb1, vbsk, vb2, vbg, vgam, vbet,
                                                  wout, outp);
}

// Round 17
// 144.891 us; speedup vs baseline: 1.0315x; 1.0315x over previous
//
#include <hip/hip_runtime.h>
#include <hip/hip_bf16.h>

#define TOK   8192      // B*T
#define NVAR  32
#define DDIM  64
#define HDIM  128
#define CDIM  64
#define ND    2048      // N*D
#define LN_EPS 1e-5f
#define TTV   32        // k_var token tile

typedef float f32x4 __attribute__((ext_vector_type(4)));
typedef short s16x8 __attribute__((ext_vector_type(8)));
typedef unsigned short u16x8 __attribute__((ext_vector_type(8)));

__device__ __forceinline__ float bf2f(unsigned short u) {
    unsigned int x = ((unsigned int)u) << 16;
    return __uint_as_float(x);
}
__device__ __forceinline__ unsigned short f2bf(float f) {
    unsigned int x = __float_as_uint(f);
    unsigned int r = (x + 0x7fffu + ((x >> 16) & 1u)) >> 16;
    return (unsigned short)r;
}
__device__ __forceinline__ float elu_f(float x) {
    return x > 0.f ? x : (__expf(x) - 1.f);
}
__device__ __forceinline__ float sigm_f(float x) {
    return 1.f / (1.f + __expf(-x));
}
__device__ __forceinline__ s16x8 frag_ld(const unsigned short* p) {
    return __builtin_bit_cast(s16x8, *(const u16x8*)p);
}
__device__ __forceinline__ f32x4 mfma_bf16(s16x8 a, s16x8 b, f32x4 c) {
    return __builtin_amdgcn_mfma_f32_16x16x32_bf16(a, b, c, 0, 0, 0);
}

// ---------------- fused pack: all 8 weight tensors -> frag-major bf16 ----------------
__global__ __launch_bounds__(256) void k_pack_all(
        const float* __restrict__ vW1, const float* __restrict__ vWsk,
        const float* __restrict__ vW2, const float* __restrict__ vWg,
        const float* __restrict__ fW1, const float* __restrict__ fWsk,
        const float* __restrict__ fW2, const float* __restrict__ fWg,
        unsigned short* __restrict__ pk1, unsigned short* __restrict__ pksk,
        unsigned short* __restrict__ pk2, unsigned short* __restrict__ pkg,
        unsigned short* __restrict__ pfW1, unsigned short* __restrict__ pfWsk,
        unsigned short* __restrict__ pfW2, unsigned short* __restrict__ pfWg) {
    int sg = blockIdx.x * 4 + (threadIdx.x >> 6);
    int lane = threadIdx.x & 63;
    const float* W; unsigned short* out; int K, N, NF, n, bx;
    if (sg < 512)       {                 W = vW1;  out = pk1;  K = 64;   N = 128; NF = 8;  n = sg >> 4;  bx = sg & 15; }
    else if (sg < 1024) { int i = sg - 512;  W = vWsk; out = pksk; K = 64;   N = 128; NF = 8;  n = i >> 4; bx = i & 15; }
    else if (sg < 2048) { int i = sg - 1024; W = vW2;  out = pk2;  K = 128;  N = 128; NF = 8;  n = i >> 5; bx = i & 31; }
    else if (sg < 4096) { int i = sg - 2048; W = vWg;  out = pkg;  K = 128;  N = 256; NF = 16; n = i >> 6; bx = i & 63; }
    else if (sg < 4608) { int i = sg - 4096; W = fW1;  out = pfW1; K = 2048; N = 128; NF = 8;  n = 0;      bx = i; }
    else if (sg < 4736) { int i = sg - 4608; W = fWsk; out = pfWsk; K = 2048; N = 32; NF = 2;  n = 0;      bx = i; }
    else if (sg < 4768) { int i = sg - 4736; W = fW2;  out = pfW2; K = 128;  N = 128; NF = 8;  n = 0;      bx = i; }
    else                { int i = sg - 4768; W = fWg;  out = pfWg; K = 128;  N = 64;  NF = 4;  n = 0;      bx = i; }
    int ks = bx / NF, nf = bx - ks * NF;
    int col = nf * 16 + (lane & 15);
    int k0 = ks * 32 + (lane >> 4) * 8;
    const float* src = W + (size_t)n * K * N + (size_t)k0 * N + col;
    unsigned short* dst = out + (size_t)n * K * N + ((size_t)bx * 64 + lane) * 8;
    unsigned short v[8];
#pragma unroll
    for (int j = 0; j < 8; ++j) v[j] = f2bf(src[(size_t)j * N]);
    *(u16x8*)dst = *(const u16x8*)v;
}

// ---------------- fused flatten GRN + selection (round-12 proven) ----------------
__global__ __launch_bounds__(256) void k_fsel(const float* __restrict__ emb,
        const float* __restrict__ ctx, const float* __restrict__ fWc,
        const unsigned short* __restrict__ pfW1, const unsigned short* __restrict__ pfWsk,
        const float* __restrict__ fb1, const float* __restrict__ fbsk,
        const unsigned short* __restrict__ pfW2, const float* __restrict__ fb2,
        const unsigned short* __restrict__ pfWg, const float* __restrict__ fbg,
        const float* __restrict__ fg, const float* __restrict__ fb,
        float* __restrict__ wout) {
    __shared__ __align__(16) unsigned short pool[21376];
    float* CTX = (float*)pool;              // [128]
    float* PRT = (float*)(pool + 256);      // [2][64][40]
    unsigned short* H1 = pool + 10496;      // [32][136]
    unsigned short* H2 = pool + 14848;      // [32][136]
    float* SK = (float*)(pool + 19200);     // [32][34]
    float* G  = (float*)(pool + 10496);     // [32][68], overlays H1 only

    const int tid = threadIdx.x;
    const int lane = tid & 63;
    const int w4 = tid >> 6;
    const int mh = w4 & 1;
    const int kh = w4 >> 1;
    const int lr = lane & 15, lk = lane >> 4;
    const int tok0 = blockIdx.x * 32;
    const int b = tok0 >> 7;

    if (tid < 128) {
        float acc0 = 0.f;
        const float* cr = ctx + b * CDIM;
#pragma unroll 8
        for (int c = 0; c < CDIM; ++c) acc0 += cr[c] * fWc[c * HDIM + tid];
        CTX[tid] = acc0;
    }

    const float* arow = emb + (size_t)(tok0 + mh * 16 + lr) * ND + kh * 1024 + lk * 8;
    f32x4 acc[10] = {};
    for (int ks = 0; ks < 32; ++ks) {
        const int ksg = kh * 32 + ks;
        float4 a0 = *(const float4*)(arow + ks * 32);
        float4 a1 = *(const float4*)(arow + ks * 32 + 4);
        unsigned short av[8];
        av[0] = f2bf(a0.x); av[1] = f2bf(a0.y); av[2] = f2bf(a0.z); av[3] = f2bf(a0.w);
        av[4] = f2bf(a1.x); av[5] = f2bf(a1.y); av[6] = f2bf(a1.z); av[7] = f2bf(a1.w);
        s16x8 af = __builtin_bit_cast(s16x8, *(u16x8*)av);
#pragma unroll
        for (int nf = 0; nf < 8; ++nf) {
            s16x8 bf = frag_ld(pfW1 + ((size_t)(ksg * 8 + nf) * 64 + lane) * 8);
            acc[nf] = mfma_bf16(af, bf, acc[nf]);
        }
#pragma unroll
        for (int nf = 0; nf < 2; ++nf) {
            s16x8 bf = frag_ld(pfWsk + ((size_t)(ksg * 2 + nf) * 64 + lane) * 8);
            acc[8 + nf] = mfma_bf16(af, bf, acc[8 + nf]);
        }
    }

    if (w4 >= 2) {
        float* p = PRT + ((size_t)mh * 64 + lane) * 40;
#pragma unroll
        for (int f = 0; f < 10; ++f) *(f32x4*)(p + f * 4) = acc[f];
    }
    __syncthreads();
    if (w4 < 2) {
        const float* p = PRT + ((size_t)mh * 64 + lane) * 40;
#pragma unroll
        for (int f = 0; f < 10; ++f) acc[f] = acc[f] + *(const f32x4*)(p + f * 4);

#pragma unroll
        for (int nf = 0; nf < 8; ++nf) {
            int col = nf * 16 + lr;
            float add = fb1[col] + CTX[col];
#pragma unroll
            for (int r = 0; r < 4; ++r)
                H1[(mh * 16 + lk * 4 + r) * 136 + col] = f2bf(elu_f(acc[nf][r] + add));
        }
#pragma unroll
        for (int nf = 0; nf < 2; ++nf) {
            int col = nf * 16 + lr;
            float add = fbsk[col];
#pragma unroll
            for (int r = 0; r < 4; ++r)
                SK[(mh * 16 + lk * 4 + r) * 34 + col] = acc[8 + nf][r] + add;
        }
    }
    __syncthreads();

    if (tid < 128) {
        const int w = w4;
        f32x4 a2[8] = {};
#pragma unroll
        for (int ks = 0; ks < 4; ++ks) {
            s16x8 af = frag_ld(H1 + (w * 16 + lr) * 136 + ks * 32 + lk * 8);
#pragma unroll
            for (int nf = 0; nf < 8; ++nf) {
                s16x8 bf = frag_ld(pfW2 + ((size_t)(ks * 8 + nf) * 64 + lane) * 8);
                a2[nf] = mfma_bf16(af, bf, a2[nf]);
            }
        }
#pragma unroll
        for (int nf = 0; nf < 8; ++nf) {
            int col = nf * 16 + lr;
            float add = fb2[col];
#pragma unroll
            for (int r = 0; r < 4; ++r)
                H2[(w * 16 + lk * 4 + r) * 136 + col] = f2bf(a2[nf][r] + add);
        }
    }
    __syncthreads();

    if (tid < 128) {
        const int w = w4;
        f32x4 a3[4] = {};
#pragma unroll
        for (int ks = 0; ks < 4; ++ks) {
            s16x8 af = frag_ld(H2 + (w * 16 + lr) * 136 + ks * 32 + lk * 8);
#pragma unroll
            for (int nf = 0; nf < 4; ++nf) {
                s16x8 bf = frag_ld(pfWg + ((size_t)(ks * 4 + nf) * 64 + lane) * 8);
                a3[nf] = mfma_bf16(af, bf, a3[nf]);
            }
        }
#pragma unroll
        for (int nf = 0; nf < 4; ++nf) {
            int col = nf * 16 + lr;
            float add = fbg[col];
#pragma unroll
            for (int r = 0; r < 4; ++r)
                G[(w * 16 + lk * 4 + r) * 68 + col] = a3[nf][r] + add;
        }
    }
    __syncthreads();

    if (tid < 128) {
        int grp = tid >> 5, t = tid & 31;
        float fgv = fg[t], fbv = fb[t];
#pragma unroll 2
        for (int j = 0; j < 8; ++j) {
            int tr = grp * 8 + j;
            float a = G[tr * 68 + t];
            float bb = G[tr * 68 + 32 + t];
            float val = a * sigm_f(bb) + SK[tr * 34 + t];
            float s = val, q = val * val;
#pragma unroll
            for (int m = 16; m >= 1; m >>= 1) { s += __shfl_xor(s, m, 32); q += __shfl_xor(q, m, 32); }
            float mean = s * (1.f / 32.f);
            float var = q * (1.f / 32.f) - mean * mean;
            float logit = (val - mean) * rsqrtf(var + LN_EPS) * fgv + fbv;
            float mx = logit;
#pragma unroll
            for (int m = 16; m >= 1; m >>= 1) mx = fmaxf(mx, __shfl_xor(mx, m, 32));
            float e = __expf(logit - mx);
            float se = e;
#pragma unroll
            for (int m = 16; m >= 1; m >>= 1) se += __shfl_xor(se, m, 32);
            wout[(size_t)(tok0 + tr) * NVAR + t] = e / se;
        }
    }
}

// ---------------- per-variable GRNs via MFMA: round-14 best configuration ----------------
// TT=32: grid dim3(256 tiles, 4 groups of 8 n) = 1024 blocks, 4 waves.
// r12's 5-section loop + cross-barrier register prefetch (the proven +13us):
//   ph1-top: prefetch ph2's 8 W2-frags -> w2p[8]
//   ph2-top: prefetch ph3's 8 Wg a-frags -> wgp[8] (b-frags inline); T14 next-n E
// LDS 14592 B: EB[32][72]@0, VHB[32][136]@2304us (VH then VH2),
//              LNp[32][4][2]f32@6656us, LNm[32][2]f32@7168us
__global__ __launch_bounds__(256, 2) void k_var(
        const float* __restrict__ emb,
        const unsigned short* __restrict__ pk1, const unsigned short* __restrict__ pksk,
        const unsigned short* __restrict__ pk2, const unsigned short* __restrict__ pkg,
        const float* __restrict__ vb1, const float* __restrict__ vbsk,
        const float* __restrict__ vb2, const float* __restrict__ vbg,
        const float* __restrict__ gam, const float* __restrict__ bet,
        const float* __restrict__ wsel, float* __restrict__ outp) {
    __shared__ __align__(16) unsigned short pool[7296];
    unsigned short* EB  = pool;                  // [32][72]
    unsigned short* VHB = pool + 2304;           // [32][136]  VH (ph1-2) then VH2 (ph2-3)
    float* LNp = (float*)(pool + 6656);          // [32][4][2]
    float* LNm = (float*)(pool + 7168);          // [32][2]

    const int tid = threadIdx.x;
    const int lane = tid & 63;
    const int w = tid >> 6;
    const int lr = lane & 15;
    const int lk = lane >> 4;
    const int tok0 = blockIdx.x * TTV;
    const int gbase = blockIdx.y * 8;

    const int prow = tid >> 3, pc0 = (tid & 7) * 8;

    float accO[2][2][4] = {};

    // ---- initial stage: E tile for n=gbase ----
    {
        const float* src = emb + ((size_t)(tok0 + prow) * NVAR + gbase) * DDIM + pc0;
        unsigned short* dst = EB + prow * 72 + pc0;
#pragma unroll
        for (int q = 0; q < 2; ++q) {
            float4 v = *(const float4*)(src + q * 4);
            ushort4 t;
            t.x = f2bf(v.x); t.y = f2bf(v.y); t.z = f2bf(v.z); t.w = f2bf(v.w);
            *(ushort4*)(dst + q * 4) = t;
        }
    }
    __syncthreads();

    for (int nn = 0; nn < 8; ++nn) {
        const int n = gbase + nn;

        // ---- prefetch ph2's B-frags (consumed after next barrier) ----
        s16x8 w2p[8];
#pragma unroll
        for (int ks = 0; ks < 4; ++ks) {
            const unsigned short* p2 = pk2 + (size_t)n * 16384 + ((size_t)(ks * 8 + w * 2) * 64 + lane) * 8;
            w2p[ks * 2]     = frag_ld(p2);
            w2p[ks * 2 + 1] = frag_ld(p2 + 512);
        }

        // ---- phase 1: VH = elu(E@W1+b1) -> VHB;  VS -> REGISTERS ----
        f32x4 c2[2][2];
#pragma unroll
        for (int mf = 0; mf < 2; ++mf)
#pragma unroll
            for (int nf = 0; nf < 2; ++nf) c2[mf][nf] = (f32x4){0.f, 0.f, 0.f, 0.f};
        {
            f32x4 c1[2][2] = {};
#pragma unroll
            for (int ks = 0; ks < 2; ++ks) {
                s16x8 af[2];
#pragma unroll
                for (int mf = 0; mf < 2; ++mf)
                    af[mf] = frag_ld(EB + (mf * 16 + lr) * 72 + ks * 32 + lk * 8);
                const unsigned short* p1 = pk1 + (size_t)n * 8192 + ((size_t)(ks * 8 + w * 2) * 64 + lane) * 8;
                const unsigned short* ps = pksk + (size_t)n * 8192 + ((size_t)(ks * 8 + w * 2) * 64 + lane) * 8;
                s16x8 b10 = frag_ld(p1), b11 = frag_ld(p1 + 512);
                s16x8 bs0 = frag_ld(ps), bs1 = frag_ld(ps + 512);
#pragma unroll
                for (int mf = 0; mf < 2; ++mf) {
                    c1[mf][0] = mfma_bf16(af[mf], b10, c1[mf][0]);
                    c1[mf][1] = mfma_bf16(af[mf], b11, c1[mf][1]);
                    c2[mf][0] = mfma_bf16(af[mf], bs0, c2[mf][0]);
                    c2[mf][1] = mfma_bf16(af[mf], bs1, c2[mf][1]);
                }
            }
#pragma unroll
            for (int nf = 0; nf < 2; ++nf) {
                int col = w * 32 + nf * 16 + lr;
                float bb1 = vb1[n * HDIM + col];
                float bbs = vbsk[n * HDIM + col];
#pragma unroll
                for (int mf = 0; mf < 2; ++mf) {
                    c2[mf][nf] = c2[mf][nf] + bbs;
#pragma unroll
                    for (int r = 0; r < 4; ++r)
                        VHB[(mf * 16 + lk * 4 + r) * 136 + col] = f2bf(elu_f(c1[mf][nf][r] + bb1));
                }
            }
        }
        __syncthreads();   // VH ready; EB dead

        // ---- prefetch ph3's Wg a-half B-frags + T14 next-n E loads ----
        s16x8 wgp[8];
#pragma unroll
        for (int ks = 0; ks < 4; ++ks) {
            const unsigned short* pg = pkg + (size_t)n * 32768;
            wgp[ks * 2]     = frag_ld(pg + ((size_t)(ks * 16 + 2 * w + 0) * 64 + lane) * 8);
            wgp[ks * 2 + 1] = frag_ld(pg + ((size_t)(ks * 16 + 2 * w + 1) * 64 + lane) * 8);
        }
        float4 pf0, pf1;
        if (nn < 7) {
            const float* src = emb + ((size_t)(tok0 + prow) * NVAR + n + 1) * DDIM + pc0;
            pf0 = *(const float4*)(src);
            pf1 = *(const float4*)(src + 4);
        }

        // ---- phase 2: VH2 = VH@W2+b2 into c3 regs (uses prefetched w2p) ----
        f32x4 c3[2][2] = {};
        {
#pragma unroll
            for (int ks = 0; ks < 4; ++ks) {
                s16x8 af[2];
#pragma unroll
                for (int mf = 0; mf < 2; ++mf)
                    af[mf] = frag_ld(VHB + (mf * 16 + lr) * 136 + ks * 32 + lk * 8);
#pragma unroll
                for (int mf = 0; mf < 2; ++mf) {
                    c3[mf][0] = mfma_bf16(af[mf], w2p[ks * 2], c3[mf][0]);
                    c3[mf][1] = mfma_bf16(af[mf], w2p[ks * 2 + 1], c3[mf][1]);
                }
            }
        }
        __syncthreads();   // all VH reads done -> VHB reusable

        // ---- write VH2 into VHB; stage prefetched E ----
        {
#pragma unroll
            for (int nf = 0; nf < 2; ++nf) {
                int col = w * 32 + nf * 16 + lr;
                float bb = vb2[n * HDIM + col];
#pragma unroll
                for (int mf = 0; mf < 2; ++mf)
#pragma unroll
                    for (int r = 0; r < 4; ++r)
                        VHB[(mf * 16 + lk * 4 + r) * 136 + col] = f2bf(c3[mf][nf][r] + bb);
            }
            if (nn < 7) {
                unsigned short* dst = EB + prow * 72 + pc0;
                ushort4 t;
                t.x = f2bf(pf0.x); t.y = f2bf(pf0.y); t.z = f2bf(pf0.z); t.w = f2bf(pf0.w);
                *(ushort4*)(dst) = t;
                t.x = f2bf(pf1.x); t.y = f2bf(pf1.y); t.z = f2bf(pf1.z); t.w = f2bf(pf1.w);
                *(ushort4*)(dst + 4) = t;
            }
        }
        __syncthreads();   // VH2 ready

        // ---- phase 3: VG in registers (a-frags from wgp, b-frags inline) ----
        float vv[2][2][4];
        float s_[2][4], q_[2][4];
        {
            f32x4 c4[2][4] = {};
#pragma unroll
            for (int ks = 0; ks < 4; ++ks) {
                s16x8 af[2];
#pragma unroll
                for (int mf = 0; mf < 2; ++mf)
                    af[mf] = frag_ld(VHB + (mf * 16 + lr) * 136 + ks * 32 + lk * 8);
                const unsigned short* pg = pkg + (size_t)n * 32768;
                s16x8 bb0 = frag_ld(pg + ((size_t)(ks * 16 + 2 * w + 8) * 64 + lane) * 8);
                s16x8 bb1 = frag_ld(pg + ((size_t)(ks * 16 + 2 * w + 9) * 64 + lane) * 8);
#pragma unroll
                for (int mf = 0; mf < 2; ++mf) {
                    c4[mf][0] = mfma_bf16(af[mf], wgp[ks * 2], c4[mf][0]);
                    c4[mf][1] = mfma_bf16(af[mf], wgp[ks * 2 + 1], c4[mf][1]);
                    c4[mf][2] = mfma_bf16(af[mf], bb0, c4[mf][2]);
                    c4[mf][3] = mfma_bf16(af[mf], bb1, c4[mf][3]);
                }
            }
            float bga0 = vbg[n * 256 + w * 32 + lr];
            float bga1 = vbg[n * 256 + w * 32 + 16 + lr];
            float bgb0 = vbg[n * 256 + 128 + w * 32 + lr];
            float bgb1 = vbg[n * 256 + 128 + w * 32 + 16 + lr];
#pragma unroll
            for (int mf = 0; mf < 2; ++mf)
#pragma unroll
                for (int r = 0; r < 4; ++r) {
                    float a0 = c4[mf][0][r] + bga0;
                    float b0 = c4[mf][2][r] + bgb0;
                    float x0 = a0 * sigm_f(b0) + c2[mf][0][r];
                    float a1 = c4[mf][1][r] + bga1;
                    float b1 = c4[mf][3][r] + bgb1;
                    float x1 = a1 * sigm_f(b1) + c2[mf][1][r];
                    vv[mf][0][r] = x0; vv[mf][1][r] = x1;
                    s_[mf][r] = x0 + x1;
                    q_[mf][r] = x0 * x0 + x1 * x1;
                }
#pragma unroll
            for (int mf = 0; mf < 2; ++mf)
#pragma unroll
                for (int r = 0; r < 4; ++r) {
#pragma unroll
                    for (int m = 1; m < 16; m <<= 1) {
                        s_[mf][r] += __shfl_xor(s_[mf][r], m);
                        q_[mf][r] += __shfl_xor(q_[mf][r], m);
                    }
                }
            if (lr == 0) {
#pragma unroll
                for (int mf = 0; mf < 2; ++mf)
#pragma unroll
                    for (int r = 0; r < 4; ++r) {
                        int row = mf * 16 + lk * 4 + r;
                        LNp[row * 8 + w * 2] = s_[mf][r];
                        LNp[row * 8 + w * 2 + 1] = q_[mf][r];
                    }
            }
        }
        __syncthreads();

        // ---- cross-wave LN finish ----
        if (tid < 128) {
            int row = tid >> 2, p = tid & 3;
            float ss = LNp[row * 8 + p * 2];
            float qq = LNp[row * 8 + p * 2 + 1];
            ss += __shfl_xor(ss, 1); qq += __shfl_xor(qq, 1);
            ss += __shfl_xor(ss, 2); qq += __shfl_xor(qq, 2);
            if (p == 0) {
                float mean = ss * (1.f / 128.f);
                float var = qq * (1.f / 128.f) - mean * mean;
                LNm[row * 2] = mean;
                LNm[row * 2 + 1] = rsqrtf(var + LN_EPS);
            }
        }
        __syncthreads();

        // ---- combine ----
        {
            float ga0 = gam[n * HDIM + w * 32 + lr];
            float ga1 = gam[n * HDIM + w * 32 + 16 + lr];
            float be0 = bet[n * HDIM + w * 32 + lr];
            float be1 = bet[n * HDIM + w * 32 + 16 + lr];
#pragma unroll
            for (int mf = 0; mf < 2; ++mf)
#pragma unroll
                for (int r = 0; r < 4; ++r) {
                    int row = mf * 16 + lk * 4 + r;
                    float mean = LNm[row * 2], inv = LNm[row * 2 + 1];
                    float wgt = wsel[(size_t)(tok0 + row) * NVAR + n];
                    accO[mf][0][r] += wgt * ((vv[mf][0][r] - mean) * inv * ga0 + be0);
                    accO[mf][1][r] += wgt * ((vv[mf][1][r] - mean) * inv * ga1 + be1);
                }
        }
    }

    // ---- one atomic per element per n-group ----
    {
#pragma unroll
        for (int mf = 0; mf < 2; ++mf)
#pragma unroll
            for (int r = 0; r < 4; ++r) {
                int row = mf * 16 + lk * 4 + r;
                float* po = outp + (size_t)(tok0 + row) * HDIM + w * 32 + lr;
                atomicAdd(po, accO[mf][0][r]);
                atomicAdd(po + 16, accO[mf][1][r]);
            }
    }
}

extern "C" void kernel_launch(void* const* d_in, const int* in_sizes, int n_in,
                              void* d_out, int out_size, void* d_ws, size_t ws_size,
                              hipStream_t stream) {
    const float* emb  = (const float*)d_in[0];
    const float* ctx  = (const float*)d_in[1];
    const float* fWsk = (const float*)d_in[2];
    const float* fbsk = (const float*)d_in[3];
    const float* fW1  = (const float*)d_in[4];
    const float* fb1  = (const float*)d_in[5];
    const float* fWc  = (const float*)d_in[6];
    const float* fW2  = (const float*)d_in[7];
    const float* fb2  = (const float*)d_in[8];
    const float* fWg  = (const float*)d_in[9];
    const float* fbg  = (const float*)d_in[10];
    const float* fg   = (const float*)d_in[11];
    const float* fb   = (const float*)d_in[12];
    const float* vWsk = (const float*)d_in[13];
    const float* vbsk = (const float*)d_in[14];
    const float* vW1  = (const float*)d_in[15];
    const float* vb1  = (const float*)d_in[16];
    const float* vW2  = (const float*)d_in[17];
    const float* vb2  = (const float*)d_in[18];
    const float* vWg  = (const float*)d_in[19];
    const float* vbg  = (const float*)d_in[20];
    const float* vgam = (const float*)d_in[21];
    const float* vbet = (const float*)d_in[22];

    float* outp = (float*)d_out;                       // [8192][128]
    float* wout = outp + (size_t)TOK * HDIM;           // [8192][32]

    unsigned short* pk1  = (unsigned short*)d_ws;      // [32][64][128]
    unsigned short* pksk = pk1 + 262144;               // [32][64][128]
    unsigned short* pk2  = pksk + 262144;              // [32][128][128]
    unsigned short* pkg  = pk2 + 524288;               // [32][128][256]
    unsigned short* pfW1 = pkg + 1048576;              // [2048][128]
    unsigned short* pfWsk= pfW1 + 262144;              // [2048][32]
    unsigned short* pfW2 = pfWsk + 65536;              // [128][128]
    unsigned short* pfWg = pfW2 + 16384;               // [128][64]

    hipMemsetAsync(d_out, 0, (size_t)TOK * HDIM * sizeof(float), stream);
    k_pack_all<<<1196, 256, 0, stream>>>(vW1, vWsk, vW2, vWg, fW1, fWsk, fW2, fWg,
                                         pk1, pksk, pk2, pkg, pfW1, pfWsk, pfW2, pfWg);
    k_fsel<<<256, 256, 0, stream>>>(emb, ctx, fWc, pfW1, pfWsk, fb1, fbsk,
                                    pfW2, fb2, pfWg, fbg, fg, fb, wout);
    k_var<<<dim3(TOK / TTV, 4), 256, 0, stream>>>(emb, pk1, pksk, pk2, pkg,
                                                  vb1, vbsk, vb2, vbg, vgam, vbet,
                                                  wout, outp);
}